// Round 1
// baseline (2027.078 us; speedup 1.0000x reference)
//
#include <hip/hip_runtime.h>
#include <math.h>

#define KSLOTS 8
#define PN     131072
#define LOC_RATIO 0.5714285714285714f

// ---- workspace layout (float offsets) ----
#define WS_ZB0   0        // [8][64]  b_b0 + W_b0[:,33:97] @ z[k]
#define WS_ZA0   512      // [8][64]  b_a0 + W_a0[:,33:97] @ z[k]
#define WS_WQB0  1024     // [64][36] W_b0[:,0:33] padded to 36 (pad=0)
#define WS_WQA0  3328     // [64][36] W_a0[:,0:33] padded to 36 (pad=0)
#define WS_WHA0  5632     // [64][64] W_a0[:,97:161]

// ---- output layout (float offsets), tuple concat order ----
#define OFF_RAWS     0            // [P,4]
#define OFF_MASKED   524288       // [K,P,4]
#define OFF_UNMASK   4718592      // [K,P,4]
#define OFF_MASKS    8912896      // [K,P]

// ============================ prep kernel ============================
__global__ void prep_kernel(const float* __restrict__ z_slots,
                            const float* __restrict__ w_b0, const float* __restrict__ b_b0,
                            const float* __restrict__ w_a0, const float* __restrict__ b_a0,
                            float* __restrict__ ws) {
    const int t = blockIdx.x * blockDim.x + threadIdx.x;
    const int nthr = gridDim.x * blockDim.x;
    // fused z-dependent biases
    for (int idx = t; idx < 512; idx += nthr) {
        const int k = idx >> 6, j = idx & 63;
        float s0 = b_b0[j], s1 = b_a0[j];
        for (int i = 0; i < 64; ++i) {
            const float zv = z_slots[k * 64 + i];
            s0 = fmaf(w_b0[j * 97 + 33 + i], zv, s0);
            s1 = fmaf(w_a0[j * 161 + 33 + i], zv, s1);
        }
        ws[WS_ZB0 + idx] = s0;
        ws[WS_ZA0 + idx] = s1;
    }
    // padded query-part weights (stride 36, 16B-aligned rows)
    for (int idx = t; idx < 64 * 36; idx += nthr) {
        const int j = idx / 36, i = idx - j * 36;
        ws[WS_WQB0 + idx] = (i < 33) ? w_b0[j * 97 + i] : 0.0f;
        ws[WS_WQA0 + idx] = (i < 33) ? w_a0[j * 161 + i] : 0.0f;
    }
    // h-part of a0 repacked contiguous
    for (int idx = t; idx < 4096; idx += nthr) {
        const int j = idx >> 6, i = idx & 63;
        ws[WS_WHA0 + idx] = w_a0[j * 161 + 97 + i];
    }
}

// ============================ main pass ============================
// thread-private LDS row, chunk-XOR swizzle to spread banks
__device__ __forceinline__ float* lds_addr(float* act, int t, int c) {
    return act + t * 64 + (((c + t) & 15) << 2);
}
__device__ __forceinline__ void lds_store4(float* act, int t, int c,
                                           float a0, float a1, float a2, float a3) {
    *(float4*)lds_addr(act, t, c) = make_float4(a0, a1, a2, a3);
}
__device__ __forceinline__ void lds_load64(float* act, int t, float (&h)[64]) {
#pragma unroll
    for (int c = 0; c < 16; ++c) {
        const float4 v = *(const float4*)lds_addr(act, t, c);
        h[4 * c + 0] = v.x; h[4 * c + 1] = v.y; h[4 * c + 2] = v.z; h[4 * c + 3] = v.w;
    }
}

template <bool RELU>
__device__ __forceinline__ void layer64(const float* __restrict__ w, const float* __restrict__ b,
                                        const float (&h)[64], float* act, int t) {
#pragma unroll 1
    for (int j = 0; j < 64; j += 4) {
        float a0 = b[j + 0], a1 = b[j + 1], a2 = b[j + 2], a3 = b[j + 3];
        const float* r0 = w + (j + 0) * 64;
        const float* r1 = w + (j + 1) * 64;
        const float* r2 = w + (j + 2) * 64;
        const float* r3 = w + (j + 3) * 64;
#pragma unroll
        for (int i = 0; i < 64; ++i) {
            const float hi = h[i];
            a0 = fmaf(r0[i], hi, a0);
            a1 = fmaf(r1[i], hi, a1);
            a2 = fmaf(r2[i], hi, a2);
            a3 = fmaf(r3[i], hi, a3);
        }
        if (RELU) {
            a0 = fmaxf(a0, 0.0f); a1 = fmaxf(a1, 0.0f);
            a2 = fmaxf(a2, 0.0f); a3 = fmaxf(a3, 0.0f);
        }
        lds_store4(act, t, j >> 2, a0, a1, a2, a3);
    }
}

__global__ __launch_bounds__(256, 2)
void fg_kernel(const float* __restrict__ coor_in,        // [K,P,3]
               const float* __restrict__ fg_transform,   // [9]
               const float* __restrict__ fg_slot_pos,    // [K,3]
               const float* __restrict__ w_b1, const float* __restrict__ b_b1,
               const float* __restrict__ w_b2, const float* __restrict__ b_b2,
               const float* __restrict__ w_a1, const float* __restrict__ b_a1,
               const float* __restrict__ w_a2, const float* __restrict__ b_a2,
               const float* __restrict__ w_lat, const float* __restrict__ b_lat,
               const float* __restrict__ w_sh, const float* __restrict__ b_sh,
               const float* __restrict__ w_c0, const float* __restrict__ b_c0,
               const float* __restrict__ w_c1, const float* __restrict__ b_c1,
               const float* __restrict__ ws,
               float* __restrict__ out) {
    __shared__ float act[256 * 64];  // 64 KB, thread-private rows, no barriers
    const int t = threadIdx.x;
    const int kk = blockIdx.x >> 9;                  // 512 blocks per slot
    const int p  = ((blockIdx.x & 511) << 8) + t;
    const long idx = (long)kk * PN + p;

    // uniform transform + slot position (scalar-cached)
    const float T00 = fg_transform[0], T01 = fg_transform[1], T02 = fg_transform[2];
    const float T10 = fg_transform[3], T11 = fg_transform[4], T12 = fg_transform[5];
    const float T20 = fg_transform[6], T21 = fg_transform[7], T22 = fg_transform[8];
    const float px = fg_slot_pos[kk * 3 + 0], py = fg_slot_pos[kk * 3 + 1], pz = fg_slot_pos[kk * 3 + 2];

    const float x = coor_in[idx * 3 + 0];
    const float y = coor_in[idx * 3 + 1];
    const float zc = coor_in[idx * 3 + 2];

    // locality mask on transform of ORIGINAL coords
    const float o0 = T00 * x + T01 * y + T02 * zc;
    const float o1 = T10 * x + T11 * y + T12 * zc;
    const float o2 = T20 * x + T21 * y + T22 * zc;
    const bool outsider = (fabsf(o0) > LOC_RATIO) || (fabsf(o1) > LOC_RATIO) || (fabsf(o2) > LOC_RATIO);

    // relative + transformed coords
    const float rx = x - px, ry = y - py, rz = zc - pz;
    const float cx = T00 * rx + T01 * ry + T02 * rz;
    const float cy = T10 * rx + T11 * ry + T12 * rz;
    const float cz = T20 * rx + T21 * ry + T22 * rz;

    // sin embedding, padded to 36 (pad entries 0, matching zero-padded weights)
    float q[36];
    q[0] = cx; q[1] = cy; q[2] = cz;
#pragma unroll
    for (int l = 0; l < 5; ++l) {
        const float f = (float)(1 << l);
        float s, c;
        sincosf(f * cx, &s, &c); q[3 + 6 * l + 0] = s; q[3 + 6 * l + 3] = c;
        sincosf(f * cy, &s, &c); q[3 + 6 * l + 1] = s; q[3 + 6 * l + 4] = c;
        sincosf(f * cz, &s, &c); q[3 + 6 * l + 2] = s; q[3 + 6 * l + 5] = c;
    }
    q[33] = 0.0f; q[34] = 0.0f; q[35] = 0.0f;

    // ---- b0: h = relu(zb0[k] + Wq_b0 @ q) ----
    {
        const float* zb0 = ws + WS_ZB0 + (kk << 6);
        const float* wq  = ws + WS_WQB0;
#pragma unroll 1
        for (int j = 0; j < 64; j += 4) {
            float a0 = zb0[j + 0], a1 = zb0[j + 1], a2 = zb0[j + 2], a3 = zb0[j + 3];
            const float* r0 = wq + (j + 0) * 36;
            const float* r1 = wq + (j + 1) * 36;
            const float* r2 = wq + (j + 2) * 36;
            const float* r3 = wq + (j + 3) * 36;
#pragma unroll
            for (int i = 0; i < 36; ++i) {
                const float qi = q[i];
                a0 = fmaf(r0[i], qi, a0);
                a1 = fmaf(r1[i], qi, a1);
                a2 = fmaf(r2[i], qi, a2);
                a3 = fmaf(r3[i], qi, a3);
            }
            lds_store4(act, t, j >> 2, fmaxf(a0, 0.f), fmaxf(a1, 0.f), fmaxf(a2, 0.f), fmaxf(a3, 0.f));
        }
    }

    float h[64];
    lds_load64(act, t, h);
    layer64<true>(w_b1, b_b1, h, act, t);
    lds_load64(act, t, h);
    layer64<true>(w_b2, b_b2, h, act, t);
    lds_load64(act, t, h);  // h = b2 output

    // ---- a0: relu(za0[k] + Wh @ h + Wq_a0 @ q) ----
    {
        const float* za0 = ws + WS_ZA0 + (kk << 6);
        const float* wh  = ws + WS_WHA0;
        const float* wq  = ws + WS_WQA0;
#pragma unroll 1
        for (int j = 0; j < 64; j += 4) {
            float a0 = za0[j + 0], a1 = za0[j + 1], a2 = za0[j + 2], a3 = za0[j + 3];
            {
                const float* r0 = wh + (j + 0) * 64;
                const float* r1 = wh + (j + 1) * 64;
                const float* r2 = wh + (j + 2) * 64;
                const float* r3 = wh + (j + 3) * 64;
#pragma unroll
                for (int i = 0; i < 64; ++i) {
                    const float hi = h[i];
                    a0 = fmaf(r0[i], hi, a0);
                    a1 = fmaf(r1[i], hi, a1);
                    a2 = fmaf(r2[i], hi, a2);
                    a3 = fmaf(r3[i], hi, a3);
                }
            }
            {
                const float* r0 = wq + (j + 0) * 36;
                const float* r1 = wq + (j + 1) * 36;
                const float* r2 = wq + (j + 2) * 36;
                const float* r3 = wq + (j + 3) * 36;
#pragma unroll
                for (int i = 0; i < 36; ++i) {
                    const float qi = q[i];
                    a0 = fmaf(r0[i], qi, a0);
                    a1 = fmaf(r1[i], qi, a1);
                    a2 = fmaf(r2[i], qi, a2);
                    a3 = fmaf(r3[i], qi, a3);
                }
            }
            lds_store4(act, t, j >> 2, fmaxf(a0, 0.f), fmaxf(a1, 0.f), fmaxf(a2, 0.f), fmaxf(a3, 0.f));
        }
    }

    lds_load64(act, t, h);
    layer64<true>(w_a1, b_a1, h, act, t);
    lds_load64(act, t, h);
    layer64<true>(w_a2, b_a2, h, act, t);
    lds_load64(act, t, h);  // h = tmp

    // ---- shape head (from tmp) ----
    float sh = b_sh[0];
#pragma unroll
    for (int i = 0; i < 64; ++i) sh = fmaf(w_sh[i], h[i], sh);
    const float sigma = outsider ? 0.0f : fmaxf(sh, 0.0f);

    // ---- latent (no relu) ----
    layer64<false>(w_lat, b_lat, h, act, t);
    float lat[64];
    lds_load64(act, t, lat);

    // ---- c0: 16 outputs (fully unrolled -> register array) ----
    float cc[16];
#pragma unroll
    for (int j = 0; j < 16; ++j) {
        float a = b_c0[j];
        const float* r = w_c0 + j * 64;
#pragma unroll
        for (int i = 0; i < 64; ++i) a = fmaf(r[i], lat[i], a);
        cc[j] = fmaxf(a, 0.0f);
    }

    // ---- c1: rgb ----
    float r0 = b_c1[0], r1 = b_c1[1], r2 = b_c1[2];
#pragma unroll
    for (int i = 0; i < 16; ++i) {
        r0 = fmaf(w_c1[i], cc[i], r0);
        r1 = fmaf(w_c1[16 + i], cc[i], r1);
        r2 = fmaf(w_c1[32 + i], cc[i], r2);
    }
    const float u0 = (tanhf(r0) + 1.0f) * 0.5f;
    const float u1 = (tanhf(r1) + 1.0f) * 0.5f;
    const float u2 = (tanhf(r2) + 1.0f) * 0.5f;

    *(float4*)(out + OFF_UNMASK + (idx << 2)) = make_float4(u0, u1, u2, sigma);
}

// ============================ compose pass ============================
__global__ __launch_bounds__(256)
void compose_kernel(float* __restrict__ out) {
    const int p = blockIdx.x * blockDim.x + threadIdx.x;  // [0, P)
    const float4* un = (const float4*)(out + OFF_UNMASK);
    float4 u[KSLOTS];
    float s = 0.0f;
#pragma unroll
    for (int k = 0; k < KSLOTS; ++k) {
        u[k] = un[k * PN + p];
        s += u[k].w;
    }
    const float denom = s + 1e-5f;
    float4* mk = (float4*)(out + OFF_MASKED);
    float* ms = out + OFF_MASKS;
    float4 r = make_float4(0.f, 0.f, 0.f, 0.f);
#pragma unroll
    for (int k = 0; k < KSLOTS; ++k) {
        const float m = u[k].w / denom;   // precise division to match reference
        ms[k * PN + p] = m;
        const float4 v = make_float4(u[k].x * m, u[k].y * m, u[k].z * m, u[k].w * m);
        mk[k * PN + p] = v;
        r.x += v.x; r.y += v.y; r.z += v.z; r.w += v.w;
    }
    ((float4*)(out + OFF_RAWS))[p] = r;
}

// ============================ launch ============================
extern "C" void kernel_launch(void* const* d_in, const int* in_sizes, int n_in,
                              void* d_out, int out_size, void* d_ws, size_t ws_size,
                              hipStream_t stream) {
    const float* coor = (const float*)d_in[0];
    const float* z    = (const float*)d_in[1];
    const float* ft   = (const float*)d_in[2];
    const float* pos  = (const float*)d_in[3];
    const float* w_b0 = (const float*)d_in[4];  const float* b_b0 = (const float*)d_in[5];
    const float* w_b1 = (const float*)d_in[6];  const float* b_b1 = (const float*)d_in[7];
    const float* w_b2 = (const float*)d_in[8];  const float* b_b2 = (const float*)d_in[9];
    const float* w_a0 = (const float*)d_in[10]; const float* b_a0 = (const float*)d_in[11];
    const float* w_a1 = (const float*)d_in[12]; const float* b_a1 = (const float*)d_in[13];
    const float* w_a2 = (const float*)d_in[14]; const float* b_a2 = (const float*)d_in[15];
    const float* w_lat = (const float*)d_in[16]; const float* b_lat = (const float*)d_in[17];
    const float* w_sh  = (const float*)d_in[18]; const float* b_sh  = (const float*)d_in[19];
    const float* w_c0  = (const float*)d_in[20]; const float* b_c0  = (const float*)d_in[21];
    const float* w_c1  = (const float*)d_in[22]; const float* b_c1  = (const float*)d_in[23];
    float* out = (float*)d_out;
    float* ws  = (float*)d_ws;

    hipLaunchKernelGGL(prep_kernel, dim3(32), dim3(256), 0, stream,
                       z, w_b0, b_b0, w_a0, b_a0, ws);
    hipLaunchKernelGGL(fg_kernel, dim3((KSLOTS * PN) / 256), dim3(256), 0, stream,
                       coor, ft, pos,
                       w_b1, b_b1, w_b2, b_b2, w_a1, b_a1, w_a2, b_a2,
                       w_lat, b_lat, w_sh, b_sh, w_c0, b_c0, w_c1, b_c1,
                       ws, out);
    hipLaunchKernelGGL(compose_kernel, dim3(PN / 256), dim3(256), 0, stream, out);
}

// Round 2
// 1098.309 us; speedup vs baseline: 1.8456x; 1.8456x over previous
//
#include <hip/hip_runtime.h>
#include <math.h>

#define KSLOTS 8
#define PN     131072
#define LOC_RATIO 0.5714285714285714f
#define TILE   32      // points per wave
#define AST    68      // A row stride (floats), padded: 4-way conflicts max in head phase
#define QST    36      // Q row stride (floats)

// ---- workspace layout (float offsets) ----
#define WS_ZB0   0        // [8][64]   b_b0 + W_b0[:,33:97] @ z[k]
#define WS_ZA0   512      // [8][64]   b_a0 + W_a0[:,33:97] @ z[k]
#define WS_QB0T  1024     // [36][64]  W_b0[:,0:33]^T padded (rows 33..35 = 0)
#define WS_QA0T  3328     // [36][64]  W_a0[:,0:33]^T padded
#define WS_HA0T  5632     // [64][64]  W_a0[:,97:161]^T
#define WS_B1T   9728     // [64][64]  W_b1^T
#define WS_B2T   13824
#define WS_A1T   17920
#define WS_A2T   22016
#define WS_LATT  26112    // end at 30208 floats (118 KB)

// ---- output layout (float offsets), tuple concat order ----
#define OFF_RAWS     0
#define OFF_MASKED   524288
#define OFF_UNMASK   4718592
#define OFF_MASKS    8912896

// ============================ prep kernel ============================
__global__ void prep_kernel(const float* __restrict__ z_slots,
                            const float* __restrict__ w_b0, const float* __restrict__ b_b0,
                            const float* __restrict__ w_a0, const float* __restrict__ b_a0,
                            const float* __restrict__ w_b1, const float* __restrict__ w_b2,
                            const float* __restrict__ w_a1, const float* __restrict__ w_a2,
                            const float* __restrict__ w_lat,
                            float* __restrict__ ws) {
    const int t = blockIdx.x * blockDim.x + threadIdx.x;
    const int nthr = gridDim.x * blockDim.x;
    // fused z-dependent biases
    for (int idx = t; idx < 512; idx += nthr) {
        const int k = idx >> 6, j = idx & 63;
        float s0 = b_b0[j], s1 = b_a0[j];
        for (int i = 0; i < 64; ++i) {
            const float zv = z_slots[k * 64 + i];
            s0 = fmaf(w_b0[j * 97 + 33 + i], zv, s0);
            s1 = fmaf(w_a0[j * 161 + 33 + i], zv, s1);
        }
        ws[WS_ZB0 + idx] = s0;
        ws[WS_ZA0 + idx] = s1;
    }
    // transposed query-part weights [i][j], rows 33..35 zero
    for (int n = t; n < 2304; n += nthr) {
        const int i = n >> 6, j = n & 63;
        ws[WS_QB0T + n] = (i < 33) ? w_b0[j * 97 + i] : 0.0f;
        ws[WS_QA0T + n] = (i < 33) ? w_a0[j * 161 + i] : 0.0f;
    }
    // transposed 64x64 weights [i][j]
    for (int n = t; n < 4096; n += nthr) {
        const int i = n >> 6, j = n & 63;
        ws[WS_HA0T + n] = w_a0[j * 161 + 97 + i];
        ws[WS_B1T + n]  = w_b1[j * 64 + i];
        ws[WS_B2T + n]  = w_b2[j * 64 + i];
        ws[WS_A1T + n]  = w_a1[j * 64 + i];
        ws[WS_A2T + n]  = w_a2[j * 64 + i];
        ws[WS_LATT + n] = w_lat[j * 64 + i];
    }
}

// ============================ main pass ============================
// Generic 64->64 layer, feature-role: lane j computes output feature j for
// all 32 points; weight row in VGPRs, activations broadcast from LDS,
// in-place row update (wave lockstep => no barrier).
__device__ __forceinline__ void layerF(float* At, const float* __restrict__ wt,
                                       float bias, int j, bool do_relu) {
    float w[64];
#pragma unroll
    for (int i = 0; i < 64; ++i) w[i] = wt[i * 64 + j];
#pragma unroll 1
    for (int g = 0; g < 8; ++g) {
        float* r0 = At + (4 * g) * AST;
        float* r1 = r0 + AST;
        float* r2 = r0 + 2 * AST;
        float* r3 = r0 + 3 * AST;
        float a0 = bias, a1 = bias, a2 = bias, a3 = bias;
#pragma unroll
        for (int i = 0; i < 64; i += 4) {
            const float4 x0 = *(const float4*)(r0 + i);
            const float4 x1 = *(const float4*)(r1 + i);
            const float4 x2 = *(const float4*)(r2 + i);
            const float4 x3 = *(const float4*)(r3 + i);
            a0 = fmaf(w[i], x0.x, a0); a0 = fmaf(w[i + 1], x0.y, a0);
            a0 = fmaf(w[i + 2], x0.z, a0); a0 = fmaf(w[i + 3], x0.w, a0);
            a1 = fmaf(w[i], x1.x, a1); a1 = fmaf(w[i + 1], x1.y, a1);
            a1 = fmaf(w[i + 2], x1.z, a1); a1 = fmaf(w[i + 3], x1.w, a1);
            a2 = fmaf(w[i], x2.x, a2); a2 = fmaf(w[i + 1], x2.y, a2);
            a2 = fmaf(w[i + 2], x2.z, a2); a2 = fmaf(w[i + 3], x2.w, a2);
            a3 = fmaf(w[i], x3.x, a3); a3 = fmaf(w[i + 1], x3.y, a3);
            a3 = fmaf(w[i + 2], x3.z, a3); a3 = fmaf(w[i + 3], x3.w, a3);
        }
        if (do_relu) {
            a0 = fmaxf(a0, 0.f); a1 = fmaxf(a1, 0.f);
            a2 = fmaxf(a2, 0.f); a3 = fmaxf(a3, 0.f);
        }
        r0[j] = a0; r1[j] = a1; r2[j] = a2; r3[j] = a3;
    }
}

__global__ __launch_bounds__(256, 3)
void fg_kernel(const float* __restrict__ coor_in,
               const float* __restrict__ fg_transform,
               const float* __restrict__ fg_slot_pos,
               const float* __restrict__ b_b1, const float* __restrict__ b_b2,
               const float* __restrict__ b_a1, const float* __restrict__ b_a2,
               const float* __restrict__ b_lat,
               const float* __restrict__ w_sh, const float* __restrict__ b_sh,
               const float* __restrict__ w_c0, const float* __restrict__ b_c0,
               const float* __restrict__ w_c1, const float* __restrict__ b_c1,
               const float* __restrict__ ws,
               float* __restrict__ out) {
    __shared__ float A[4 * TILE * AST];   // 34816 B
    __shared__ float Q[4 * TILE * QST];   // 18432 B  (total 52 KB -> 3 blocks/CU)
    const int lane = threadIdx.x & 63;
    const int wv = threadIdx.x >> 6;
    const int tile = blockIdx.x * 4 + wv;
    const int kk = tile >> 12;            // 4096 tiles per slot
    const int p0 = (tile & 4095) << 5;    // tile base point
    float* At = A + wv * (TILE * AST);
    float* Qt = Q + wv * (TILE * QST);

    // ---- phase 0: point-role, split across lane halves ----
    bool outsider = false;
    {
        const int pl = lane & 31;
        const int half = lane >> 5;
        const long idx = (long)kk * PN + p0 + pl;
        const float x = coor_in[idx * 3 + 0];
        const float y = coor_in[idx * 3 + 1];
        const float zc = coor_in[idx * 3 + 2];
        const float T00 = fg_transform[0], T01 = fg_transform[1], T02 = fg_transform[2];
        const float T10 = fg_transform[3], T11 = fg_transform[4], T12 = fg_transform[5];
        const float T20 = fg_transform[6], T21 = fg_transform[7], T22 = fg_transform[8];
        const float px = fg_slot_pos[kk * 3 + 0], py = fg_slot_pos[kk * 3 + 1], pz = fg_slot_pos[kk * 3 + 2];
        const float rx = x - px, ry = y - py, rz = zc - pz;
        const float cx = T00 * rx + T01 * ry + T02 * rz;
        const float cy = T10 * rx + T11 * ry + T12 * rz;
        const float cz = T20 * rx + T21 * ry + T22 * rz;
        float* qr = Qt + pl * QST;
        if (half == 0) {
            const float o0 = T00 * x + T01 * y + T02 * zc;
            const float o1 = T10 * x + T11 * y + T12 * zc;
            const float o2 = T20 * x + T21 * y + T22 * zc;
            outsider = (fabsf(o0) > LOC_RATIO) || (fabsf(o1) > LOC_RATIO) || (fabsf(o2) > LOC_RATIO);
            qr[0] = cx; qr[1] = cy; qr[2] = cz;
            float s, c;
#pragma unroll
            for (int l = 0; l < 2; ++l) {
                const float f = (float)(1 << l);
                sincosf(f * cx, &s, &c); qr[3 + 6 * l + 0] = s; qr[3 + 6 * l + 3] = c;
                sincosf(f * cy, &s, &c); qr[3 + 6 * l + 1] = s; qr[3 + 6 * l + 4] = c;
                sincosf(f * cz, &s, &c); qr[3 + 6 * l + 2] = s; qr[3 + 6 * l + 5] = c;
            }
        } else {
            float s, c;
#pragma unroll
            for (int l = 2; l < 5; ++l) {
                const float f = (float)(1 << l);
                sincosf(f * cx, &s, &c); qr[3 + 6 * l + 0] = s; qr[3 + 6 * l + 3] = c;
                sincosf(f * cy, &s, &c); qr[3 + 6 * l + 1] = s; qr[3 + 6 * l + 4] = c;
                sincosf(f * cz, &s, &c); qr[3 + 6 * l + 2] = s; qr[3 + 6 * l + 5] = c;
            }
            qr[33] = 0.0f; qr[34] = 0.0f; qr[35] = 0.0f;
        }
    }

    // ---- b0: feature-role, in 36 (Q) -> out 64 (A) ----
    {
        float w[36];
#pragma unroll
        for (int i = 0; i < 36; ++i) w[i] = ws[WS_QB0T + i * 64 + lane];
        const float bias = ws[WS_ZB0 + (kk << 6) + lane];
#pragma unroll 1
        for (int g = 0; g < 8; ++g) {
            const float* q0 = Qt + (4 * g) * QST;
            const float* q1 = q0 + QST;
            const float* q2 = q0 + 2 * QST;
            const float* q3 = q0 + 3 * QST;
            float a0 = bias, a1 = bias, a2 = bias, a3 = bias;
#pragma unroll
            for (int i = 0; i < 36; i += 4) {
                const float4 x0 = *(const float4*)(q0 + i);
                const float4 x1 = *(const float4*)(q1 + i);
                const float4 x2 = *(const float4*)(q2 + i);
                const float4 x3 = *(const float4*)(q3 + i);
                a0 = fmaf(w[i], x0.x, a0); a0 = fmaf(w[i + 1], x0.y, a0);
                a0 = fmaf(w[i + 2], x0.z, a0); a0 = fmaf(w[i + 3], x0.w, a0);
                a1 = fmaf(w[i], x1.x, a1); a1 = fmaf(w[i + 1], x1.y, a1);
                a1 = fmaf(w[i + 2], x1.z, a1); a1 = fmaf(w[i + 3], x1.w, a1);
                a2 = fmaf(w[i], x2.x, a2); a2 = fmaf(w[i + 1], x2.y, a2);
                a2 = fmaf(w[i + 2], x2.z, a2); a2 = fmaf(w[i + 3], x2.w, a2);
                a3 = fmaf(w[i], x3.x, a3); a3 = fmaf(w[i + 1], x3.y, a3);
                a3 = fmaf(w[i + 2], x3.z, a3); a3 = fmaf(w[i + 3], x3.w, a3);
            }
            float* r0 = At + (4 * g) * AST;
            r0[lane] = fmaxf(a0, 0.f);
            (r0 + AST)[lane] = fmaxf(a1, 0.f);
            (r0 + 2 * AST)[lane] = fmaxf(a2, 0.f);
            (r0 + 3 * AST)[lane] = fmaxf(a3, 0.f);
        }
    }

    // ---- b1, b2 ----
    {
        const float* wts[2] = { ws + WS_B1T, ws + WS_B2T };
        const float* bs[2] = { b_b1, b_b2 };
#pragma unroll 1
        for (int L = 0; L < 2; ++L) layerF(At, wts[L], bs[L][lane], lane, true);
    }

    // ---- a0: in 64 (A, in place) + 36 (Q) ----
    {
        float wh[64], wq[36];
#pragma unroll
        for (int i = 0; i < 64; ++i) wh[i] = ws[WS_HA0T + i * 64 + lane];
#pragma unroll
        for (int i = 0; i < 36; ++i) wq[i] = ws[WS_QA0T + i * 64 + lane];
        const float bias = ws[WS_ZA0 + (kk << 6) + lane];
#pragma unroll 1
        for (int g = 0; g < 8; ++g) {
            float* r0 = At + (4 * g) * AST;
            float* r1 = r0 + AST;
            float* r2 = r0 + 2 * AST;
            float* r3 = r0 + 3 * AST;
            const float* q0 = Qt + (4 * g) * QST;
            const float* q1 = q0 + QST;
            const float* q2 = q0 + 2 * QST;
            const float* q3 = q0 + 3 * QST;
            float a0 = bias, a1 = bias, a2 = bias, a3 = bias;
#pragma unroll
            for (int i = 0; i < 64; i += 4) {
                const float4 x0 = *(const float4*)(r0 + i);
                const float4 x1 = *(const float4*)(r1 + i);
                const float4 x2 = *(const float4*)(r2 + i);
                const float4 x3 = *(const float4*)(r3 + i);
                a0 = fmaf(wh[i], x0.x, a0); a0 = fmaf(wh[i + 1], x0.y, a0);
                a0 = fmaf(wh[i + 2], x0.z, a0); a0 = fmaf(wh[i + 3], x0.w, a0);
                a1 = fmaf(wh[i], x1.x, a1); a1 = fmaf(wh[i + 1], x1.y, a1);
                a1 = fmaf(wh[i + 2], x1.z, a1); a1 = fmaf(wh[i + 3], x1.w, a1);
                a2 = fmaf(wh[i], x2.x, a2); a2 = fmaf(wh[i + 1], x2.y, a2);
                a2 = fmaf(wh[i + 2], x2.z, a2); a2 = fmaf(wh[i + 3], x2.w, a2);
                a3 = fmaf(wh[i], x3.x, a3); a3 = fmaf(wh[i + 1], x3.y, a3);
                a3 = fmaf(wh[i + 2], x3.z, a3); a3 = fmaf(wh[i + 3], x3.w, a3);
            }
#pragma unroll
            for (int i = 0; i < 36; i += 4) {
                const float4 x0 = *(const float4*)(q0 + i);
                const float4 x1 = *(const float4*)(q1 + i);
                const float4 x2 = *(const float4*)(q2 + i);
                const float4 x3 = *(const float4*)(q3 + i);
                a0 = fmaf(wq[i], x0.x, a0); a0 = fmaf(wq[i + 1], x0.y, a0);
                a0 = fmaf(wq[i + 2], x0.z, a0); a0 = fmaf(wq[i + 3], x0.w, a0);
                a1 = fmaf(wq[i], x1.x, a1); a1 = fmaf(wq[i + 1], x1.y, a1);
                a1 = fmaf(wq[i + 2], x1.z, a1); a1 = fmaf(wq[i + 3], x1.w, a1);
                a2 = fmaf(wq[i], x2.x, a2); a2 = fmaf(wq[i + 1], x2.y, a2);
                a2 = fmaf(wq[i + 2], x2.z, a2); a2 = fmaf(wq[i + 3], x2.w, a2);
                a3 = fmaf(wq[i], x3.x, a3); a3 = fmaf(wq[i + 1], x3.y, a3);
                a3 = fmaf(wq[i + 2], x3.z, a3); a3 = fmaf(wq[i + 3], x3.w, a3);
            }
            r0[lane] = fmaxf(a0, 0.f);
            r1[lane] = fmaxf(a1, 0.f);
            r2[lane] = fmaxf(a2, 0.f);
            r3[lane] = fmaxf(a3, 0.f);
        }
    }

    // ---- a1, a2 ----
    {
        const float* wts[2] = { ws + WS_A1T, ws + WS_A2T };
        const float* bs[2] = { b_a1, b_a2 };
#pragma unroll 1
        for (int L = 0; L < 2; ++L) layerF(At, wts[L], bs[L][lane], lane, true);
    }

    // ---- shape head from tmp (A), point-role half-wave, keep sh in reg ----
    float sh = 0.0f;
    if (lane < 32) {
        const float* r = At + lane * AST;
        sh = b_sh[0];
#pragma unroll
        for (int i = 0; i < 64; i += 4) {
            const float4 v = *(const float4*)(r + i);
            sh = fmaf(w_sh[i], v.x, sh); sh = fmaf(w_sh[i + 1], v.y, sh);
            sh = fmaf(w_sh[i + 2], v.z, sh); sh = fmaf(w_sh[i + 3], v.w, sh);
        }
    }

    // ---- latent (no relu), overwrites A in place ----
    layerF(At, ws + WS_LATT, b_lat[lane], lane, false);

    // ---- heads: point-role half-wave ----
    if (lane < 32) {
        const float* r = At + lane * AST;
        float lv[64];
#pragma unroll
        for (int i = 0; i < 64; i += 4) {
            const float4 v = *(const float4*)(r + i);
            lv[i] = v.x; lv[i + 1] = v.y; lv[i + 2] = v.z; lv[i + 3] = v.w;
        }
        float cc[16];
#pragma unroll 1
        for (int j = 0; j < 16; ++j) {
            float a = b_c0[j];
            const float* wr = w_c0 + j * 64;
#pragma unroll
            for (int i = 0; i < 64; ++i) a = fmaf(wr[i], lv[i], a);
            cc[j] = fmaxf(a, 0.0f);
        }
        float r0 = b_c1[0], r1 = b_c1[1], r2 = b_c1[2];
#pragma unroll
        for (int i = 0; i < 16; ++i) {
            r0 = fmaf(w_c1[i], cc[i], r0);
            r1 = fmaf(w_c1[16 + i], cc[i], r1);
            r2 = fmaf(w_c1[32 + i], cc[i], r2);
        }
        const float u0 = (tanhf(r0) + 1.0f) * 0.5f;
        const float u1 = (tanhf(r1) + 1.0f) * 0.5f;
        const float u2 = (tanhf(r2) + 1.0f) * 0.5f;
        const float sigma = outsider ? 0.0f : fmaxf(sh, 0.0f);
        const long idx = (long)kk * PN + p0 + lane;
        *(float4*)(out + OFF_UNMASK + (idx << 2)) = make_float4(u0, u1, u2, sigma);
    }
}

// ============================ compose pass ============================
__global__ __launch_bounds__(256)
void compose_kernel(float* __restrict__ out) {
    const int p = blockIdx.x * blockDim.x + threadIdx.x;
    const float4* un = (const float4*)(out + OFF_UNMASK);
    float4 u[KSLOTS];
    float s = 0.0f;
#pragma unroll
    for (int k = 0; k < KSLOTS; ++k) {
        u[k] = un[k * PN + p];
        s += u[k].w;
    }
    const float denom = s + 1e-5f;
    float4* mk = (float4*)(out + OFF_MASKED);
    float* ms = out + OFF_MASKS;
    float4 r = make_float4(0.f, 0.f, 0.f, 0.f);
#pragma unroll
    for (int k = 0; k < KSLOTS; ++k) {
        const float m = u[k].w / denom;
        ms[k * PN + p] = m;
        const float4 v = make_float4(u[k].x * m, u[k].y * m, u[k].z * m, u[k].w * m);
        mk[k * PN + p] = v;
        r.x += v.x; r.y += v.y; r.z += v.z; r.w += v.w;
    }
    ((float4*)(out + OFF_RAWS))[p] = r;
}

// ============================ launch ============================
extern "C" void kernel_launch(void* const* d_in, const int* in_sizes, int n_in,
                              void* d_out, int out_size, void* d_ws, size_t ws_size,
                              hipStream_t stream) {
    const float* coor = (const float*)d_in[0];
    const float* z    = (const float*)d_in[1];
    const float* ft   = (const float*)d_in[2];
    const float* pos  = (const float*)d_in[3];
    const float* w_b0 = (const float*)d_in[4];  const float* b_b0 = (const float*)d_in[5];
    const float* w_b1 = (const float*)d_in[6];  const float* b_b1 = (const float*)d_in[7];
    const float* w_b2 = (const float*)d_in[8];  const float* b_b2 = (const float*)d_in[9];
    const float* w_a0 = (const float*)d_in[10]; const float* b_a0 = (const float*)d_in[11];
    const float* w_a1 = (const float*)d_in[12]; const float* b_a1 = (const float*)d_in[13];
    const float* w_a2 = (const float*)d_in[14]; const float* b_a2 = (const float*)d_in[15];
    const float* w_lat = (const float*)d_in[16]; const float* b_lat = (const float*)d_in[17];
    const float* w_sh  = (const float*)d_in[18]; const float* b_sh  = (const float*)d_in[19];
    const float* w_c0  = (const float*)d_in[20]; const float* b_c0  = (const float*)d_in[21];
    const float* w_c1  = (const float*)d_in[22]; const float* b_c1  = (const float*)d_in[23];
    float* out = (float*)d_out;
    float* ws  = (float*)d_ws;

    hipLaunchKernelGGL(prep_kernel, dim3(64), dim3(256), 0, stream,
                       z, w_b0, b_b0, w_a0, b_a0, w_b1, w_b2, w_a1, w_a2, w_lat, ws);
    hipLaunchKernelGGL(fg_kernel, dim3((KSLOTS * PN / TILE) / 4), dim3(256), 0, stream,
                       coor, ft, pos,
                       b_b1, b_b2, b_a1, b_a2, b_lat,
                       w_sh, b_sh, w_c0, b_c0, w_c1, b_c1,
                       ws, out);
    hipLaunchKernelGGL(compose_kernel, dim3(PN / 256), dim3(256), 0, stream, out);
}

// Round 3
// 422.641 us; speedup vs baseline: 4.7962x; 2.5987x over previous
//
#include <hip/hip_runtime.h>
#include <math.h>

#define KSLOTS 8
#define PN     131072
#define LOC_RATIO 0.5714285714285714f
#define AST    68
#define INV2048 4.8828125e-4f

typedef _Float16 half8 __attribute__((ext_vector_type(8)));
typedef float floatx4 __attribute__((ext_vector_type(4)));

#define MFMA(A_,B_,C_) __builtin_amdgcn_mfma_f32_16x16x32_f16(A_,B_,C_,0,0,0)

// ---- workspace layout (float offsets) ----
// frag area: 34 ntiles x 2 ks x 2 term x 64 lanes x 8 f16  = 34816 floats
#define WS_ZB0  34816   // [8][64]
#define WS_ZA0  35328   // [8][64]
#define WS_BST  35840   // b1@0 b2@64 a1@128 a2@192 latsh@256(80) c0@336(16)

// global ntile bases: b0q=0 b1=4 b2=8 a0q=12 a0h=16 a1=20 a2=24 latsh=28(5) c0=33
// entry (half8 units) = gnt*256 + ks*128 + term*64 + lane  == (gnt*4+ks*2+term)*64+lane

// ---- output layout (float offsets) ----
#define OFF_RAWS     0
#define OFF_MASKED   524288
#define OFF_UNMASK   4718592
#define OFF_MASKS    8912896

// ============================ prep kernel ============================
__global__ void prep_kernel(const float* __restrict__ z_slots,
                            const float* __restrict__ w_b0, const float* __restrict__ b_b0,
                            const float* __restrict__ w_b1, const float* __restrict__ b_b1,
                            const float* __restrict__ w_b2, const float* __restrict__ b_b2,
                            const float* __restrict__ w_a0, const float* __restrict__ b_a0,
                            const float* __restrict__ w_a1, const float* __restrict__ b_a1,
                            const float* __restrict__ w_a2, const float* __restrict__ b_a2,
                            const float* __restrict__ w_lat, const float* __restrict__ b_lat,
                            const float* __restrict__ w_sh, const float* __restrict__ b_sh,
                            const float* __restrict__ w_c0, const float* __restrict__ b_c0,
                            float* __restrict__ ws) {
    const int tid = blockIdx.x * blockDim.x + threadIdx.x;
    if (tid < 8704) {
        // one thread per fragment register set (8 f16 values)
        const int lane = tid & 63;
        const int term = (tid >> 6) & 1;
        const int ks   = (tid >> 7) & 1;
        const int gnt  = tid >> 8;           // 0..33
        // decode unit
        int u, ntl;
        if      (gnt < 4)  { u = 0; ntl = gnt; }
        else if (gnt < 8)  { u = 1; ntl = gnt - 4; }
        else if (gnt < 12) { u = 2; ntl = gnt - 8; }
        else if (gnt < 16) { u = 3; ntl = gnt - 12; }
        else if (gnt < 20) { u = 4; ntl = gnt - 16; }
        else if (gnt < 24) { u = 5; ntl = gnt - 20; }
        else if (gnt < 28) { u = 6; ntl = gnt - 24; }
        else if (gnt < 33) { u = 7; ntl = gnt - 28; }
        else               { u = 8; ntl = 0; }
        const int n = lane & 15, quad = lane >> 4;
        const int jo = ntl * 16 + n;
        half8 frag;
#pragma unroll
        for (int j = 0; j < 8; ++j) {
            const int k = ks * 32 + quad * 8 + j;
            float w = 0.0f;
            switch (u) {
                case 0: if (k < 33) w = w_b0[jo * 97 + k]; break;
                case 1: w = w_b1[jo * 64 + k]; break;
                case 2: w = w_b2[jo * 64 + k]; break;
                case 3: if (k < 33) w = w_a0[jo * 161 + k]; break;
                case 4: w = w_a0[jo * 161 + 97 + k]; break;
                case 5: w = w_a1[jo * 64 + k]; break;
                case 6: w = w_a2[jo * 64 + k]; break;
                case 7: w = (jo < 64) ? w_lat[jo * 64 + k]
                          : ((jo == 64) ? w_sh[k] : 0.0f); break;
                default: w = w_c0[jo * 64 + k]; break;
            }
            const _Float16 hi = (_Float16)w;
            frag[j] = (term == 0) ? hi : (_Float16)((w - (float)hi) * 2048.0f);
        }
        ((half8*)ws)[tid] = frag;
    } else if (tid < 9216) {
        const int idx = tid - 8704;            // 0..511
        const int k = idx >> 6, j = idx & 63;
        float s0 = b_b0[j], s1 = b_a0[j];
        for (int i = 0; i < 64; ++i) {
            const float zv = z_slots[k * 64 + i];
            s0 = fmaf(w_b0[j * 97 + 33 + i], zv, s0);
            s1 = fmaf(w_a0[j * 161 + 33 + i], zv, s1);
        }
        ws[WS_ZB0 + idx] = s0;
        ws[WS_ZA0 + idx] = s1;
    } else if (tid < 9568) {
        const int idx = tid - 9216;            // 0..351
        float v;
        if      (idx < 64)  v = b_b1[idx];
        else if (idx < 128) v = b_b2[idx - 64];
        else if (idx < 192) v = b_a1[idx - 128];
        else if (idx < 256) v = b_a2[idx - 192];
        else if (idx < 336) { const int j = idx - 256; v = (j < 64) ? b_lat[j] : ((j == 64) ? b_sh[0] : 0.0f); }
        else                v = b_c0[idx - 336];
        ws[WS_BST + idx] = v;
    }
}

// ============================ main pass helpers ============================
__device__ __forceinline__ void split8(const floatx4 va, const floatx4 vb, half8& h, half8& l) {
#pragma unroll
    for (int j = 0; j < 4; ++j) {
        const float a = va[j];
        const _Float16 ha = (_Float16)a;
        h[j] = ha;
        l[j] = (_Float16)((a - (float)ha) * 2048.0f);
    }
#pragma unroll
    for (int j = 0; j < 4; ++j) {
        const float a = vb[j];
        const _Float16 ha = (_Float16)a;
        h[4 + j] = ha;
        l[4 + j] = (_Float16)((a - (float)ha) * 2048.0f);
    }
}

// load this lane's A-fragments (both k-steps, hi+lo) from an LDS activation row
__device__ __forceinline__ void frag_from_lds(const float* row, int quad,
                                              half8& h0, half8& l0, half8& h1, half8& l1) {
    const floatx4 v0 = *(const floatx4*)(row + quad * 8);
    const floatx4 v1 = *(const floatx4*)(row + quad * 8 + 4);
    const floatx4 v2 = *(const floatx4*)(row + 32 + quad * 8);
    const floatx4 v3 = *(const floatx4*)(row + 32 + quad * 8 + 4);
    split8(v0, v1, h0, l0);
    split8(v2, v3, h1, l1);
}

// standard 64->64 unit: 4 ntiles, 6 MFMAs each
__device__ __forceinline__ void hidden4(float* Aw,
                                        const half8 h0, const half8 l0, const half8 h1, const half8 l1,
                                        int gnt0, const float* __restrict__ bias, bool relu,
                                        const half8* __restrict__ fragp, int lane) {
    const int col = lane & 15, quad = lane >> 4;
#pragma unroll
    for (int nt = 0; nt < 4; ++nt) {
        const float bv = bias[nt * 16 + col];
        floatx4 a0v = {bv, bv, bv, bv};
        floatx4 am  = {0.f, 0.f, 0.f, 0.f};
        const int e = (gnt0 + nt) * 4;
        const half8 bh0 = fragp[(e + 0) * 64 + lane];
        const half8 bl0 = fragp[(e + 1) * 64 + lane];
        const half8 bh1 = fragp[(e + 2) * 64 + lane];
        const half8 bl1 = fragp[(e + 3) * 64 + lane];
        a0v = MFMA(h0, bh0, a0v); am = MFMA(h0, bl0, am); am = MFMA(l0, bh0, am);
        a0v = MFMA(h1, bh1, a0v); am = MFMA(h1, bl1, am); am = MFMA(l1, bh1, am);
#pragma unroll
        for (int r = 0; r < 4; ++r) {
            float v = fmaf(am[r], INV2048, a0v[r]);
            if (relu) v = fmaxf(v, 0.0f);
            Aw[(quad * 4 + r) * AST + nt * 16 + col] = v;
        }
    }
}

// ============================ main kernel ============================
__global__ __launch_bounds__(256, 4)
void fg_kernel(const float* __restrict__ coor_in,
               const float* __restrict__ fg_transform,
               const float* __restrict__ fg_slot_pos,
               const float* __restrict__ w_c1, const float* __restrict__ b_c1,
               const float* __restrict__ ws,
               float* __restrict__ out) {
    __shared__ float A[4 * 16 * AST];
    __shared__ float Q[4 * 16 * AST];
    const int lane = threadIdx.x & 63;
    const int wv   = threadIdx.x >> 6;
    const int tile = blockIdx.x * 4 + wv;
    const int kk = tile >> 13;            // 8192 tiles per slot
    const int p0 = (tile & 8191) << 4;
    float* Aw = A + wv * (16 * AST);
    float* Qw = Q + wv * (16 * AST);
    const half8* fragp = (const half8*)ws;
    const int col = lane & 15, quad = lane >> 4;

    // ---- phase 0: build q[16][64] (padded) + outsider stash ----
    {
        const int p = lane & 15;
        const int part = lane >> 4;
        const long idx3 = ((long)kk * PN + p0 + p) * 3;
        const float x = coor_in[idx3 + 0];
        const float y = coor_in[idx3 + 1];
        const float zc = coor_in[idx3 + 2];
        const float T00 = fg_transform[0], T01 = fg_transform[1], T02 = fg_transform[2];
        const float T10 = fg_transform[3], T11 = fg_transform[4], T12 = fg_transform[5];
        const float T20 = fg_transform[6], T21 = fg_transform[7], T22 = fg_transform[8];
        const float px = fg_slot_pos[kk * 3 + 0], py = fg_slot_pos[kk * 3 + 1], pz = fg_slot_pos[kk * 3 + 2];
        const float rx = x - px, ry = y - py, rz = zc - pz;
        const float cx = T00 * rx + T01 * ry + T02 * rz;
        const float cy = T10 * rx + T11 * ry + T12 * rz;
        const float cz = T20 * rx + T21 * ry + T22 * rz;
        float* qr = Qw + p * AST;
        float s, c;
        if (part == 0) {
            const float o0 = T00 * x + T01 * y + T02 * zc;
            const float o1 = T10 * x + T11 * y + T12 * zc;
            const float o2 = T20 * x + T21 * y + T22 * zc;
            const bool outs = (fabsf(o0) > LOC_RATIO) || (fabsf(o1) > LOC_RATIO) || (fabsf(o2) > LOC_RATIO);
            qr[0] = cx; qr[1] = cy; qr[2] = cz;
            qr[33] = 0.0f; qr[34] = 0.0f; qr[35] = 0.0f;
            qr[64] = outs ? 1.0f : 0.0f;
        } else if (part == 1) {
#pragma unroll
            for (int l = 0; l < 2; ++l) {
                const float f = (float)(1 << l);
                sincosf(f * cx, &s, &c); qr[3 + 6 * l + 0] = s; qr[3 + 6 * l + 3] = c;
                sincosf(f * cy, &s, &c); qr[3 + 6 * l + 1] = s; qr[3 + 6 * l + 4] = c;
                sincosf(f * cz, &s, &c); qr[3 + 6 * l + 2] = s; qr[3 + 6 * l + 5] = c;
            }
        } else if (part == 2) {
#pragma unroll
            for (int l = 2; l < 4; ++l) {
                const float f = (float)(1 << l);
                sincosf(f * cx, &s, &c); qr[3 + 6 * l + 0] = s; qr[3 + 6 * l + 3] = c;
                sincosf(f * cy, &s, &c); qr[3 + 6 * l + 1] = s; qr[3 + 6 * l + 4] = c;
                sincosf(f * cz, &s, &c); qr[3 + 6 * l + 2] = s; qr[3 + 6 * l + 5] = c;
            }
        } else {
            sincosf(16.0f * cx, &s, &c); qr[27] = s; qr[30] = c;
            sincosf(16.0f * cy, &s, &c); qr[28] = s; qr[31] = c;
            sincosf(16.0f * cz, &s, &c); qr[29] = s; qr[32] = c;
#pragma unroll
            for (int cch = 9; cch < 16; ++cch)
                *(floatx4*)(qr + cch * 4) = (floatx4){0.f, 0.f, 0.f, 0.f};  // zero feats 36..63
        }
    }

    // ---- q fragments (kept in registers for b0 AND a0) ----
    half8 qh0, ql0, qh1, ql1;
    frag_from_lds(Qw + (lane & 15) * AST, quad, qh0, ql0, qh1, ql1);

    // ---- b0 ----
    hidden4(Aw, qh0, ql0, qh1, ql1, 0, ws + WS_ZB0 + kk * 64, true, fragp, lane);

    half8 h0, l0, h1, l1;
    // ---- b1, b2 ----
    frag_from_lds(Aw + (lane & 15) * AST, quad, h0, l0, h1, l1);
    hidden4(Aw, h0, l0, h1, l1, 4, ws + WS_BST + 0, true, fragp, lane);
    frag_from_lds(Aw + (lane & 15) * AST, quad, h0, l0, h1, l1);
    hidden4(Aw, h0, l0, h1, l1, 8, ws + WS_BST + 64, true, fragp, lane);

    // ---- a0: q part (gnt 12..15) + h part (gnt 16..19), bias za0 ----
    frag_from_lds(Aw + (lane & 15) * AST, quad, h0, l0, h1, l1);
    {
        const float* bias = ws + WS_ZA0 + kk * 64;
#pragma unroll
        for (int nt = 0; nt < 4; ++nt) {
            const float bv = bias[nt * 16 + col];
            floatx4 a0v = {bv, bv, bv, bv};
            floatx4 am  = {0.f, 0.f, 0.f, 0.f};
            {
                const int e = (12 + nt) * 4;
                const half8 bh0 = fragp[(e + 0) * 64 + lane];
                const half8 bl0 = fragp[(e + 1) * 64 + lane];
                const half8 bh1 = fragp[(e + 2) * 64 + lane];
                const half8 bl1 = fragp[(e + 3) * 64 + lane];
                a0v = MFMA(qh0, bh0, a0v); am = MFMA(qh0, bl0, am); am = MFMA(ql0, bh0, am);
                a0v = MFMA(qh1, bh1, a0v); am = MFMA(qh1, bl1, am); am = MFMA(ql1, bh1, am);
            }
            {
                const int e = (16 + nt) * 4;
                const half8 bh0 = fragp[(e + 0) * 64 + lane];
                const half8 bl0 = fragp[(e + 1) * 64 + lane];
                const half8 bh1 = fragp[(e + 2) * 64 + lane];
                const half8 bl1 = fragp[(e + 3) * 64 + lane];
                a0v = MFMA(h0, bh0, a0v); am = MFMA(h0, bl0, am); am = MFMA(l0, bh0, am);
                a0v = MFMA(h1, bh1, a0v); am = MFMA(h1, bl1, am); am = MFMA(l1, bh1, am);
            }
#pragma unroll
            for (int r = 0; r < 4; ++r) {
                float v = fmaf(am[r], INV2048, a0v[r]);
                v = fmaxf(v, 0.0f);
                Aw[(quad * 4 + r) * AST + nt * 16 + col] = v;
            }
        }
    }

    // ---- a1, a2 ----
    frag_from_lds(Aw + (lane & 15) * AST, quad, h0, l0, h1, l1);
    hidden4(Aw, h0, l0, h1, l1, 20, ws + WS_BST + 128, true, fragp, lane);
    frag_from_lds(Aw + (lane & 15) * AST, quad, h0, l0, h1, l1);
    hidden4(Aw, h0, l0, h1, l1, 24, ws + WS_BST + 192, true, fragp, lane);

    // ---- lat (4 ntiles, no relu) + shape column (5th ntile) ----
    frag_from_lds(Aw + (lane & 15) * AST, quad, h0, l0, h1, l1);
    {
        const float* bias = ws + WS_BST + 256;   // latsh[80]
#pragma unroll
        for (int nt = 0; nt < 5; ++nt) {
            const float bv = bias[nt * 16 + col];
            floatx4 a0v = {bv, bv, bv, bv};
            floatx4 am  = {0.f, 0.f, 0.f, 0.f};
            const int e = (28 + nt) * 4;
            const half8 bh0 = fragp[(e + 0) * 64 + lane];
            const half8 bl0 = fragp[(e + 1) * 64 + lane];
            const half8 bh1 = fragp[(e + 2) * 64 + lane];
            const half8 bl1 = fragp[(e + 3) * 64 + lane];
            a0v = MFMA(h0, bh0, a0v); am = MFMA(h0, bl0, am); am = MFMA(l0, bh0, am);
            a0v = MFMA(h1, bh1, a0v); am = MFMA(h1, bl1, am); am = MFMA(l1, bh1, am);
            if (nt < 4) {
#pragma unroll
                for (int r = 0; r < 4; ++r) {
                    const float v = fmaf(am[r], INV2048, a0v[r]);   // no relu
                    Aw[(quad * 4 + r) * AST + nt * 16 + col] = v;
                }
            } else {
                if (col == 0) {
#pragma unroll
                    for (int r = 0; r < 4; ++r) {
                        const float v = fmaf(am[r], INV2048, a0v[r]);  // sigma pre-relu
                        Aw[(quad * 4 + r) * AST + 64] = v;
                    }
                }
            }
        }
    }

    // ---- c0: 64 -> 16, relu, write cc to Q ----
    frag_from_lds(Aw + (lane & 15) * AST, quad, h0, l0, h1, l1);
    {
        const float* bias = ws + WS_BST + 336;
        const float bv = bias[col];
        floatx4 a0v = {bv, bv, bv, bv};
        floatx4 am  = {0.f, 0.f, 0.f, 0.f};
        const int e = 33 * 4;
        const half8 bh0 = fragp[(e + 0) * 64 + lane];
        const half8 bl0 = fragp[(e + 1) * 64 + lane];
        const half8 bh1 = fragp[(e + 2) * 64 + lane];
        const half8 bl1 = fragp[(e + 3) * 64 + lane];
        a0v = MFMA(h0, bh0, a0v); am = MFMA(h0, bl0, am); am = MFMA(l0, bh0, am);
        a0v = MFMA(h1, bh1, a0v); am = MFMA(h1, bl1, am); am = MFMA(l1, bh1, am);
#pragma unroll
        for (int r = 0; r < 4; ++r) {
            const float v = fmaxf(fmaf(am[r], INV2048, a0v[r]), 0.0f);
            Qw[(quad * 4 + r) * AST + col] = v;
        }
    }

    // ---- heads: lane = p*4 + o ----
    {
        const int p = lane >> 2, o = lane & 3;
        float v;
        if (o < 3) {
            const float* cr = Qw + p * AST;
            float a = b_c1[o];
#pragma unroll
            for (int i = 0; i < 16; ++i) a = fmaf(w_c1[o * 16 + i], cr[i], a);
            v = (tanhf(a) + 1.0f) * 0.5f;
        } else {
            const float sig = Aw[p * AST + 64];
            const float outs = Qw[p * AST + 64];
            v = (outs > 0.5f) ? 0.0f : fmaxf(sig, 0.0f);
        }
        const long idx = (long)kk * PN + p0 + p;
        out[OFF_UNMASK + (idx << 2) + o] = v;
    }
}

// ============================ compose pass ============================
__global__ __launch_bounds__(256)
void compose_kernel(float* __restrict__ out) {
    const int p = blockIdx.x * blockDim.x + threadIdx.x;
    const float4* un = (const float4*)(out + OFF_UNMASK);
    float4 u[KSLOTS];
    float s = 0.0f;
#pragma unroll
    for (int k = 0; k < KSLOTS; ++k) {
        u[k] = un[k * PN + p];
        s += u[k].w;
    }
    const float denom = s + 1e-5f;
    float4* mk = (float4*)(out + OFF_MASKED);
    float* ms = out + OFF_MASKS;
    float4 r = make_float4(0.f, 0.f, 0.f, 0.f);
#pragma unroll
    for (int k = 0; k < KSLOTS; ++k) {
        const float m = u[k].w / denom;
        ms[k * PN + p] = m;
        const float4 v = make_float4(u[k].x * m, u[k].y * m, u[k].z * m, u[k].w * m);
        mk[k * PN + p] = v;
        r.x += v.x; r.y += v.y; r.z += v.z; r.w += v.w;
    }
    ((float4*)(out + OFF_RAWS))[p] = r;
}

// ============================ launch ============================
extern "C" void kernel_launch(void* const* d_in, const int* in_sizes, int n_in,
                              void* d_out, int out_size, void* d_ws, size_t ws_size,
                              hipStream_t stream) {
    const float* coor = (const float*)d_in[0];
    const float* z    = (const float*)d_in[1];
    const float* ft   = (const float*)d_in[2];
    const float* pos  = (const float*)d_in[3];
    const float* w_b0 = (const float*)d_in[4];  const float* b_b0 = (const float*)d_in[5];
    const float* w_b1 = (const float*)d_in[6];  const float* b_b1 = (const float*)d_in[7];
    const float* w_b2 = (const float*)d_in[8];  const float* b_b2 = (const float*)d_in[9];
    const float* w_a0 = (const float*)d_in[10]; const float* b_a0 = (const float*)d_in[11];
    const float* w_a1 = (const float*)d_in[12]; const float* b_a1 = (const float*)d_in[13];
    const float* w_a2 = (const float*)d_in[14]; const float* b_a2 = (const float*)d_in[15];
    const float* w_lat = (const float*)d_in[16]; const float* b_lat = (const float*)d_in[17];
    const float* w_sh  = (const float*)d_in[18]; const float* b_sh  = (const float*)d_in[19];
    const float* w_c0  = (const float*)d_in[20]; const float* b_c0  = (const float*)d_in[21];
    const float* w_c1  = (const float*)d_in[22]; const float* b_c1  = (const float*)d_in[23];
    float* out = (float*)d_out;
    float* ws  = (float*)d_ws;

    hipLaunchKernelGGL(prep_kernel, dim3(38), dim3(256), 0, stream,
                       z,
                       w_b0, b_b0, w_b1, b_b1, w_b2, b_b2,
                       w_a0, b_a0, w_a1, b_a1, w_a2, b_a2,
                       w_lat, b_lat, w_sh, b_sh, w_c0, b_c0, ws);
    hipLaunchKernelGGL(fg_kernel, dim3((KSLOTS * PN / 16) / 4), dim3(256), 0, stream,
                       coor, ft, pos, w_c1, b_c1, ws, out);
    hipLaunchKernelGGL(compose_kernel, dim3(PN / 256), dim3(256), 0, stream, out);
}

// Round 5
// 397.443 us; speedup vs baseline: 5.1003x; 1.0634x over previous
//
#include <hip/hip_runtime.h>
#include <math.h>

#define KSLOTS 8
#define PN     131072
#define LOC_RATIO 0.5714285714285714f
#define INV2048 4.8828125e-4f

typedef _Float16 f16x8 __attribute__((ext_vector_type(8)));
typedef __fp16 pk16x2 __attribute__((ext_vector_type(2)));
typedef float floatx4 __attribute__((ext_vector_type(4)));
union F4H8 { int4 i; f16x8 h; };
union PK2I { pk16x2 h; int i; };

#define MFMA(A_,B_,C_) __builtin_amdgcn_mfma_f32_16x16x32_f16(A_,B_,C_,0,0,0)

// ---- B-fragment pair bases (each pair = bh,bl slots; slot = e*2+term) ----
#define EB_B0   0
#define EB_B1   4
#define EB_B2   12
#define EB_A0Q  20
#define EB_A0H  24
#define EB_A1   32
#define EB_A2   40
#define EB_LAT  48
#define EB_C0   58
// frag region: 60 pairs * 2 slots * 64 lanes * 4 dw = 30720 dwords
#define WS_ZB0  30720   // [8][64] f32
#define WS_ZA0  31232
#define WS_BST  31744   // b1@0 b2@64 a1@128 a2@192 latsh@256(80) c0@336(16)
#define WS_W32  32096   // wb0_col32[64], wa0_col32[64]

// ---- output layout (float offsets) ----
#define OFF_RAWS     0
#define OFF_MASKED   524288
#define OFF_UNMASK   4718592
#define OFF_MASKS    8912896

// ============================ prep kernel ============================
__global__ void prep_kernel(const float* __restrict__ z_slots,
                            const float* __restrict__ w_b0, const float* __restrict__ b_b0,
                            const float* __restrict__ w_b1, const float* __restrict__ b_b1,
                            const float* __restrict__ w_b2, const float* __restrict__ b_b2,
                            const float* __restrict__ w_a0, const float* __restrict__ b_a0,
                            const float* __restrict__ w_a1, const float* __restrict__ b_a1,
                            const float* __restrict__ w_a2, const float* __restrict__ b_a2,
                            const float* __restrict__ w_lat, const float* __restrict__ b_lat,
                            const float* __restrict__ w_sh, const float* __restrict__ b_sh,
                            const float* __restrict__ w_c0, const float* __restrict__ b_c0,
                            float* __restrict__ ws) {
    const int tid = blockIdx.x * blockDim.x + threadIdx.x;
    if (tid < 7680) {
        const int lane = tid & 63;
        const int term = (tid >> 6) & 1;
        const int e    = tid >> 7;         // 0..59
        int u, nt, ks;
        if      (e < 4)  { u = 0; nt = e;            ks = 0; }
        else if (e < 12) { u = 1; nt = (e-4)  >> 1;  ks = (e-4)  & 1; }
        else if (e < 20) { u = 2; nt = (e-12) >> 1;  ks = (e-12) & 1; }
        else if (e < 24) { u = 3; nt = e - 20;       ks = 0; }
        else if (e < 32) { u = 4; nt = (e-24) >> 1;  ks = (e-24) & 1; }
        else if (e < 40) { u = 5; nt = (e-32) >> 1;  ks = (e-32) & 1; }
        else if (e < 48) { u = 6; nt = (e-40) >> 1;  ks = (e-40) & 1; }
        else if (e < 58) { u = 7; nt = (e-48) >> 1;  ks = (e-48) & 1; }
        else             { u = 8; nt = 0;            ks = e - 58; }
        const int jo = nt * 16 + (lane & 15);
        const int quad = lane >> 4;
        f16x8 frag;
#pragma unroll
        for (int j = 0; j < 8; ++j) {
            const int k = ks * 32 + quad * 8 + j;
            float w = 0.0f;
            switch (u) {
                case 0: w = w_b0[jo * 97 + k]; break;          // k<32
                case 1: w = w_b1[jo * 64 + k]; break;
                case 2: w = w_b2[jo * 64 + k]; break;
                case 3: w = w_a0[jo * 161 + k]; break;         // k<32
                case 4: w = w_a0[jo * 161 + 97 + k]; break;
                case 5: w = w_a1[jo * 64 + k]; break;
                case 6: w = w_a2[jo * 64 + k]; break;
                case 7: w = (jo < 64) ? w_lat[jo * 64 + k]
                          : ((jo == 64) ? w_sh[k] : 0.0f); break;
                default: w = w_c0[jo * 64 + k]; break;
            }
            const _Float16 hi = (_Float16)w;
            frag[j] = (term == 0) ? hi : (_Float16)((w - (float)hi) * 2048.0f);
        }
        ((f16x8*)ws)[tid] = frag;
    } else if (tid < 8192) {
        const int idx = tid - 7680;            // 0..511
        const int k = idx >> 6, j = idx & 63;
        float s0 = b_b0[j], s1 = b_a0[j];
        for (int i = 0; i < 64; ++i) {
            const float zv = z_slots[k * 64 + i];
            s0 = fmaf(w_b0[j * 97 + 33 + i], zv, s0);
            s1 = fmaf(w_a0[j * 161 + 33 + i], zv, s1);
        }
        ws[WS_ZB0 + idx] = s0;
        ws[WS_ZA0 + idx] = s1;
    } else if (tid < 8544) {
        const int idx = tid - 8192;            // 0..351
        float v;
        if      (idx < 64)  v = b_b1[idx];
        else if (idx < 128) v = b_b2[idx - 64];
        else if (idx < 192) v = b_a1[idx - 128];
        else if (idx < 256) v = b_a2[idx - 192];
        else if (idx < 336) { const int j = idx - 256; v = (j < 64) ? b_lat[j] : ((j == 64) ? b_sh[0] : 0.0f); }
        else                v = b_c0[idx - 336];
        ws[WS_BST + idx] = v;
    } else if (tid < 8672) {
        const int idx = tid - 8544;            // 0..127
        const int j = idx & 63;
        ws[WS_W32 + idx] = (idx < 64) ? w_b0[j * 97 + 32] : w_a0[j * 161 + 32];
    }
}

// ============================ device helpers ============================
__device__ __forceinline__ f16x8 rdfrag(const int* plane, int addr, unsigned sel) {
    const int4 a = *(const int4*)(plane + addr);
    const int4 b = *(const int4*)(plane + addr + 4);
    F4H8 u;
    u.i.x = __builtin_amdgcn_perm(a.y, a.x, sel);
    u.i.y = __builtin_amdgcn_perm(a.w, a.z, sel);
    u.i.z = __builtin_amdgcn_perm(b.y, b.x, sel);
    u.i.w = __builtin_amdgcn_perm(b.w, b.z, sel);
    return u.h;
}

__device__ __forceinline__ f16x8 ldB(const int* ws_i, int slot, int lane) {
    F4H8 u;
    u.i = ((const int4*)ws_i)[slot * 64 + lane];
    return u.h;
}

__device__ __forceinline__ int pkrtz_i(float a, float b) {
    PK2I u;
    u.h = __builtin_amdgcn_cvt_pkrtz(a, b);
    return u.i;
}

__device__ __forceinline__ void st_split(int* AHw, int* ALw, int addr, floatx4 v) {
    const PK2I h01 = { __builtin_amdgcn_cvt_pkrtz(v[0], v[1]) };
    const PK2I h23 = { __builtin_amdgcn_cvt_pkrtz(v[2], v[3]) };
    const float f0 = (float)h01.h.x, f1 = (float)h01.h.y;
    const float f2 = (float)h23.h.x, f3 = (float)h23.h.y;
    AHw[addr]      = h01.i;
    AHw[addr + 68] = h23.i;
    ALw[addr]      = pkrtz_i((v[0]-f0)*2048.f, (v[1]-f1)*2048.f);
    ALw[addr + 68] = pkrtz_i((v[2]-f2)*2048.f, (v[3]-f3)*2048.f);
}

__device__ __forceinline__ void st_pk16(int* QHw, int* QLw, int dwbase, int halfsel, int feat, float v) {
    const _Float16 h = (_Float16)v;
    const float hf = (float)h;
    const _Float16 l = (_Float16)((v - hf) * 2048.0f);
    ((unsigned short*)QHw)[(dwbase + feat) * 2 + halfsel] = __builtin_bit_cast(unsigned short, h);
    ((unsigned short*)QLw)[(dwbase + feat) * 2 + halfsel] = __builtin_bit_cast(unsigned short, l);
}

// ============================ main kernel ============================
__global__ __launch_bounds__(256, 4)
void fg_kernel(const float* __restrict__ coor_in,
               const float* __restrict__ fg_transform,
               const float* __restrict__ fg_slot_pos,
               const float* __restrict__ w_c1, const float* __restrict__ b_c1,
               const float* __restrict__ ws,
               float* __restrict__ out) {
    __shared__ int LB[4][2080];
    const int lane = threadIdx.x & 63;
    const int wv   = threadIdx.x >> 6;
    const int tile = blockIdx.x * 4 + wv;
    const int kk = tile >> 13;            // 8192 tiles per slot
    const int p0 = (tile & 8191) << 4;

    int* AHw = LB[wv];
    int* ALw = LB[wv] + 544;
    int* QHw = LB[wv] + 1088;
    int* QLw = LB[wv] + 1376;
    float* Q32w  = (float*)(LB[wv] + 1664);
    float* OUTSw = (float*)(LB[wv] + 1680);
    float* SIGw  = (float*)(LB[wv] + 1696);
    float* CCw   = (float*)(LB[wv] + 1712);

    const int* ws_i = (const int*)ws;
    const int n = lane & 15, quad = lane >> 4;
    const unsigned sel = (n & 1) ? 0x07060302u : 0x05040100u;
    const int rdA = (n >> 1) * 68 + quad * 8;
    const int rdQ = (n >> 1) * 36 + quad * 8;
    const int wrA = (2 * quad) * 68 + n;

    // ---- phase 0: embedding, non-divergent (role = quad, point = n) ----
    {
        const int p = n;
        const int role = quad;
        const long idx3 = ((long)kk * PN + p0 + p) * 3;
        const float x = coor_in[idx3 + 0];
        const float y = coor_in[idx3 + 1];
        const float zc = coor_in[idx3 + 2];
        const float T00 = fg_transform[0], T01 = fg_transform[1], T02 = fg_transform[2];
        const float T10 = fg_transform[3], T11 = fg_transform[4], T12 = fg_transform[5];
        const float T20 = fg_transform[6], T21 = fg_transform[7], T22 = fg_transform[8];
        if (role < 3) {
            const float px = fg_slot_pos[kk*3+0], py = fg_slot_pos[kk*3+1], pz = fg_slot_pos[kk*3+2];
            const float rx = x - px, ry = y - py, rz = zc - pz;
            const float cx = T00*rx + T01*ry + T02*rz;
            const float cy = T10*rx + T11*ry + T12*rz;
            const float cz = T20*rx + T21*ry + T22*rz;
            const float c = (role == 0) ? cx : ((role == 1) ? cy : cz);
            const int dwb = (p >> 1) * 36;
            const int hs = p & 1;
            st_pk16(QHw, QLw, dwb, hs, role, c);
            const float rev = c * 0.15915494309189535f;
            const float fr = rev - floorf(rev);
            float s  = __builtin_amdgcn_sinf(fr);
            float co = __builtin_amdgcn_cosf(fr);
#pragma unroll
            for (int l = 0; l < 5; ++l) {
                st_pk16(QHw, QLw, dwb, hs, 3 + 6*l + role, s);
                if (l == 4 && role == 2) {
                    Q32w[p] = co;                       // q[32] = cos(16 z), fp32
                } else {
                    st_pk16(QHw, QLw, dwb, hs, 6 + 6*l + role, co);
                }
                if (l < 4) {
                    const float t = s * co;
                    const float s2 = s * s;
                    co = fmaf(-2.0f, s2, 1.0f);
                    s  = t + t;
                }
            }
        } else {
            const float o0 = T00*x + T01*y + T02*zc;
            const float o1 = T10*x + T11*y + T12*zc;
            const float o2 = T20*x + T21*y + T22*zc;
            const bool outs = (fabsf(o0) > LOC_RATIO) || (fabsf(o1) > LOC_RATIO) || (fabsf(o2) > LOC_RATIO);
            OUTSw[p] = outs ? 1.0f : 0.0f;
        }
    }

    // ---- q fragments (K=32, registers, reused by b0 and a0) ----
    const f16x8 qh0 = rdfrag(QHw, rdQ, sel);
    const f16x8 ql0 = rdfrag(QLw, rdQ, sel);
    floatx4 q32v;
#pragma unroll
    for (int r = 0; r < 4; ++r) q32v[r] = Q32w[quad * 4 + r];

    // ---- b0: q(K=32) + rank-1 q32 ----
    {
        const float* zb0 = ws + WS_ZB0 + kk * 64;
        const float* w32p = ws + WS_W32;
#pragma unroll
        for (int nt = 0; nt < 4; ++nt) {
            const float bv = zb0[nt * 16 + n];
            const float w32 = w32p[nt * 16 + n];
            floatx4 acc = {bv, bv, bv, bv};
            floatx4 am  = {0.f, 0.f, 0.f, 0.f};
            const int e = EB_B0 + nt;
            const f16x8 bh = ldB(ws_i, e*2+0, lane);
            const f16x8 bl = ldB(ws_i, e*2+1, lane);
            acc = MFMA(qh0, bh, acc); am = MFMA(qh0, bl, am); am = MFMA(ql0, bh, am);
            floatx4 v;
#pragma unroll
            for (int r = 0; r < 4; ++r) {
                float t = fmaf(am[r], INV2048, acc[r]);
                t = fmaf(w32, q32v[r], t);
                v[r] = fmaxf(t, 0.0f);
            }
            st_split(AHw, ALw, wrA + nt * 16, v);
        }
    }

    // ---- generic 64->64 hidden units ----
    f16x8 h0, l0, h1, l1;
#define RD_A() do { \
        h0 = rdfrag(AHw, rdA, sel);      l0 = rdfrag(ALw, rdA, sel); \
        h1 = rdfrag(AHw, rdA + 32, sel); l1 = rdfrag(ALw, rdA + 32, sel); \
    } while (0)

#define UNIT64(EBASE, BIASP, RELU) do { \
        const float* _b = (BIASP); \
        _Pragma("unroll") \
        for (int nt = 0; nt < 4; ++nt) { \
            const float bv = _b[nt * 16 + n]; \
            floatx4 acc = {bv, bv, bv, bv}; \
            floatx4 am  = {0.f, 0.f, 0.f, 0.f}; \
            const int e0 = (EBASE) + nt * 2; \
            const f16x8 bh0 = ldB(ws_i, e0*2+0, lane); \
            const f16x8 bl0 = ldB(ws_i, e0*2+1, lane); \
            const f16x8 bh1 = ldB(ws_i, e0*2+2, lane); \
            const f16x8 bl1 = ldB(ws_i, e0*2+3, lane); \
            acc = MFMA(h0, bh0, acc); am = MFMA(h0, bl0, am); am = MFMA(l0, bh0, am); \
            acc = MFMA(h1, bh1, acc); am = MFMA(h1, bl1, am); am = MFMA(l1, bh1, am); \
            floatx4 v; \
            _Pragma("unroll") \
            for (int r = 0; r < 4; ++r) { \
                float t = fmaf(am[r], INV2048, acc[r]); \
                v[r] = (RELU) ? fmaxf(t, 0.0f) : t; \
            } \
            st_split(AHw, ALw, wrA + nt * 16, v); \
        } \
    } while (0)

    RD_A(); UNIT64(EB_B1, ws + WS_BST + 0,   true);
    RD_A(); UNIT64(EB_B2, ws + WS_BST + 64,  true);

    // ---- a0: h-part (K=64) + q-part (K=32) + rank-1 ----
    RD_A();
    {
        const float* za0 = ws + WS_ZA0 + kk * 64;
        const float* w32p = ws + WS_W32 + 64;
#pragma unroll
        for (int nt = 0; nt < 4; ++nt) {
            const float bv = za0[nt * 16 + n];
            const float w32 = w32p[nt * 16 + n];
            floatx4 acc = {bv, bv, bv, bv};
            floatx4 am  = {0.f, 0.f, 0.f, 0.f};
            {
                const int e = EB_A0Q + nt;
                const f16x8 bh = ldB(ws_i, e*2+0, lane);
                const f16x8 bl = ldB(ws_i, e*2+1, lane);
                acc = MFMA(qh0, bh, acc); am = MFMA(qh0, bl, am); am = MFMA(ql0, bh, am);
            }
            {
                const int e0 = EB_A0H + nt * 2;
                const f16x8 bh0 = ldB(ws_i, e0*2+0, lane);
                const f16x8 bl0 = ldB(ws_i, e0*2+1, lane);
                const f16x8 bh1 = ldB(ws_i, e0*2+2, lane);
                const f16x8 bl1 = ldB(ws_i, e0*2+3, lane);
                acc = MFMA(h0, bh0, acc); am = MFMA(h0, bl0, am); am = MFMA(l0, bh0, am);
                acc = MFMA(h1, bh1, acc); am = MFMA(h1, bl1, am); am = MFMA(l1, bh1, am);
            }
            floatx4 v;
#pragma unroll
            for (int r = 0; r < 4; ++r) {
                float t = fmaf(am[r], INV2048, acc[r]);
                t = fmaf(w32, q32v[r], t);
                v[r] = fmaxf(t, 0.0f);
            }
            st_split(AHw, ALw, wrA + nt * 16, v);
        }
    }

    RD_A(); UNIT64(EB_A1, ws + WS_BST + 128, true);
    RD_A(); UNIT64(EB_A2, ws + WS_BST + 192, true);

    // ---- latent (4 ntiles, no relu) + shape (5th ntile -> SIG) ----
    RD_A();
    {
        const float* bias = ws + WS_BST + 256;   // latsh[80]
#pragma unroll
        for (int nt = 0; nt < 5; ++nt) {
            const float bv = bias[nt * 16 + n];
            floatx4 acc = {bv, bv, bv, bv};
            floatx4 am  = {0.f, 0.f, 0.f, 0.f};
            const int e0 = EB_LAT + nt * 2;
            const f16x8 bh0 = ldB(ws_i, e0*2+0, lane);
            const f16x8 bl0 = ldB(ws_i, e0*2+1, lane);
            const f16x8 bh1 = ldB(ws_i, e0*2+2, lane);
            const f16x8 bl1 = ldB(ws_i, e0*2+3, lane);
            acc = MFMA(h0, bh0, acc); am = MFMA(h0, bl0, am); am = MFMA(l0, bh0, am);
            acc = MFMA(h1, bh1, acc); am = MFMA(h1, bl1, am); am = MFMA(l1, bh1, am);
            if (nt < 4) {
                floatx4 v;
#pragma unroll
                for (int r = 0; r < 4; ++r) v[r] = fmaf(am[r], INV2048, acc[r]);
                st_split(AHw, ALw, wrA + nt * 16, v);
            } else if (n == 0) {
#pragma unroll
                for (int r = 0; r < 4; ++r)
                    SIGw[quad * 4 + r] = fmaf(am[r], INV2048, acc[r]);   // sigma pre-relu
            }
        }
    }

    // ---- c0: 64 -> 16, relu, fp32 to CC ----
    RD_A();
    {
        const float* bias = ws + WS_BST + 336;
        const float bv = bias[n];
        floatx4 acc = {bv, bv, bv, bv};
        floatx4 am  = {0.f, 0.f, 0.f, 0.f};
        const f16x8 bh0 = ldB(ws_i, (EB_C0+0)*2+0, lane);
        const f16x8 bl0 = ldB(ws_i, (EB_C0+0)*2+1, lane);
        const f16x8 bh1 = ldB(ws_i, (EB_C0+1)*2+0, lane);
        const f16x8 bl1 = ldB(ws_i, (EB_C0+1)*2+1, lane);
        acc = MFMA(h0, bh0, acc); am = MFMA(h0, bl0, am); am = MFMA(l0, bh0, am);
        acc = MFMA(h1, bh1, acc); am = MFMA(h1, bl1, am); am = MFMA(l1, bh1, am);
#pragma unroll
        for (int r = 0; r < 4; ++r)
            CCw[(quad * 4 + r) * 20 + n] = fmaxf(fmaf(am[r], INV2048, acc[r]), 0.0f);
    }

    // ---- heads: lane = p*4 + o ----
    {
        const int p = lane >> 2, o = lane & 3;
        float v;
        if (o < 3) {
            const float* cr = CCw + p * 20;
            float a = b_c1[o];
#pragma unroll
            for (int i = 0; i < 16; ++i) a = fmaf(w_c1[o * 16 + i], cr[i], a);
            v = (tanhf(a) + 1.0f) * 0.5f;
        } else {
            const float sig = SIGw[p];
            const float outs = OUTSw[p];
            v = (outs > 0.5f) ? 0.0f : fmaxf(sig, 0.0f);
        }
        const long idx = (long)kk * PN + p0 + p;
        out[OFF_UNMASK + (idx << 2) + o] = v;
    }
#undef RD_A
#undef UNIT64
}

// ============================ compose pass ============================
__global__ __launch_bounds__(256)
void compose_kernel(float* __restrict__ out) {
    const int p = blockIdx.x * blockDim.x + threadIdx.x;
    const float4* un = (const float4*)(out + OFF_UNMASK);
    float4 u[KSLOTS];
    float s = 0.0f;
#pragma unroll
    for (int k = 0; k < KSLOTS; ++k) {
        u[k] = un[k * PN + p];
        s += u[k].w;
    }
    const float denom = s + 1e-5f;
    float4* mk = (float4*)(out + OFF_MASKED);
    float* ms = out + OFF_MASKS;
    float4 r = make_float4(0.f, 0.f, 0.f, 0.f);
#pragma unroll
    for (int k = 0; k < KSLOTS; ++k) {
        const float m = u[k].w / denom;
        ms[k * PN + p] = m;
        const float4 v = make_float4(u[k].x * m, u[k].y * m, u[k].z * m, u[k].w * m);
        mk[k * PN + p] = v;
        r.x += v.x; r.y += v.y; r.z += v.z; r.w += v.w;
    }
    ((float4*)(out + OFF_RAWS))[p] = r;
}

// ============================ launch ============================
extern "C" void kernel_launch(void* const* d_in, const int* in_sizes, int n_in,
                              void* d_out, int out_size, void* d_ws, size_t ws_size,
                              hipStream_t stream) {
    const float* coor = (const float*)d_in[0];
    const float* z    = (const float*)d_in[1];
    const float* ft   = (const float*)d_in[2];
    const float* pos  = (const float*)d_in[3];
    const float* w_b0 = (const float*)d_in[4];  const float* b_b0 = (const float*)d_in[5];
    const float* w_b1 = (const float*)d_in[6];  const float* b_b1 = (const float*)d_in[7];
    const float* w_b2 = (const float*)d_in[8];  const float* b_b2 = (const float*)d_in[9];
    const float* w_a0 = (const float*)d_in[10]; const float* b_a0 = (const float*)d_in[11];
    const float* w_a1 = (const float*)d_in[12]; const float* b_a1 = (const float*)d_in[13];
    const float* w_a2 = (const float*)d_in[14]; const float* b_a2 = (const float*)d_in[15];
    const float* w_lat = (const float*)d_in[16]; const float* b_lat = (const float*)d_in[17];
    const float* w_sh  = (const float*)d_in[18]; const float* b_sh  = (const float*)d_in[19];
    const float* w_c0  = (const float*)d_in[20]; const float* b_c0  = (const float*)d_in[21];
    const float* w_c1  = (const float*)d_in[22]; const float* b_c1  = (const float*)d_in[23];
    float* out = (float*)d_out;
    float* ws  = (float*)d_ws;

    hipLaunchKernelGGL(prep_kernel, dim3(34), dim3(256), 0, stream,
                       z,
                       w_b0, b_b0, w_b1, b_b1, w_b2, b_b2,
                       w_a0, b_a0, w_a1, b_a1, w_a2, b_a2,
                       w_lat, b_lat, w_sh, b_sh, w_c0, b_c0, ws);
    hipLaunchKernelGGL(fg_kernel, dim3((KSLOTS * PN / 16) / 4), dim3(256), 0, stream,
                       coor, ft, pos, w_c1, b_c1, ws, out);
    hipLaunchKernelGGL(compose_kernel, dim3(PN / 256), dim3(256), 0, stream, out);
}